// Round 1
// baseline (710.077 us; speedup 1.0000x reference)
//
#include <hip/hip_runtime.h>
#include <hip/hip_bf16.h>

#define B_ 4
#define T_ 2048
#define C_ 1024
#define NH_ 16
#define FF_ 4096
#define NT_ (B_*T_)   // 8192 token rows

typedef short bf16x8 __attribute__((ext_vector_type(8)));
typedef float f32x4 __attribute__((ext_vector_type(4)));

#define LDS_AS(p) ((__attribute__((address_space(3))) uint32_t*)(p))
#define GLB_AS(p) ((const __attribute__((address_space(1))) uint32_t*)(p))

__device__ __forceinline__ float bf2f(__hip_bfloat16 v){ return __bfloat162float(v); }
__device__ __forceinline__ __hip_bfloat16 f2bf(float f){ return __float2bfloat16(f); }

__device__ __forceinline__ f32x4 mfma16(bf16x8 a, bf16x8 b, f32x4 c){
  return __builtin_amdgcn_mfma_f32_16x16x32_bf16(a, b, c, 0, 0, 0);
}

// ---------------- weight transpose + fp32->bf16 cast:  in[K][N] -> out[N][K] ----------------
__global__ __launch_bounds__(256) void transpose_bf16(const float* __restrict__ in,
                                                      __hip_bfloat16* __restrict__ out,
                                                      int K, int N) {
  __shared__ float tile[32][33];
  const int n0 = blockIdx.x * 32, k0 = blockIdx.y * 32;
  const int x = threadIdx.x & 31, y = threadIdx.x >> 5;   // y in 0..7
  #pragma unroll
  for (int i = 0; i < 4; i++)
    tile[y + 8*i][x] = in[(size_t)(k0 + y + 8*i) * N + n0 + x];
  __syncthreads();
  #pragma unroll
  for (int i = 0; i < 4; i++)
    out[(size_t)(n0 + y + 8*i) * K + k0 + x] = f2bf(tile[x][y + 8*i]);
}

// ---------------- LayerNorm fp32 -> bf16 (row = 1024) ----------------
__global__ __launch_bounds__(256) void ln_bf16(const float* __restrict__ x,
                                               const float* __restrict__ g,
                                               const float* __restrict__ b,
                                               __hip_bfloat16* __restrict__ out) {
  const int row = blockIdx.x;
  const int tid = threadIdx.x;
  float4 v = ((const float4*)(x + (size_t)row * C_))[tid];
  float s  = v.x + v.y + v.z + v.w;
  float s2 = v.x*v.x + v.y*v.y + v.z*v.z + v.w*v.w;
  #pragma unroll
  for (int off = 32; off > 0; off >>= 1) {
    s  += __shfl_down(s,  off, 64);
    s2 += __shfl_down(s2, off, 64);
  }
  __shared__ float red[8];
  const int w = tid >> 6, l = tid & 63;
  if (l == 0) { red[w] = s; red[4 + w] = s2; }
  __syncthreads();
  s  = red[0] + red[1] + red[2] + red[3];
  s2 = red[4] + red[5] + red[6] + red[7];
  const float mu   = s * (1.0f / C_);
  const float var  = s2 * (1.0f / C_) - mu * mu;
  const float rstd = rsqrtf(var + 1e-5f);
  float4 gv = ((const float4*)g)[tid];
  float4 bv = ((const float4*)b)[tid];
  ushort4 o;
  __hip_bfloat16 t;
  t = f2bf((v.x - mu) * rstd * gv.x + bv.x); o.x = *(unsigned short*)&t;
  t = f2bf((v.y - mu) * rstd * gv.y + bv.y); o.y = *(unsigned short*)&t;
  t = f2bf((v.z - mu) * rstd * gv.z + bv.z); o.z = *(unsigned short*)&t;
  t = f2bf((v.w - mu) * rstd * gv.w + bv.w); o.w = *(unsigned short*)&t;
  ((ushort4*)out)[(size_t)row * (C_/4) + tid] = o;
}

// ---------------- shared MFMA GEMM, BK=64, XOR-swizzled staging ----------------
// C[M][N] = A[M][K] * BT[N][K]^T + epilogue
// MODE 0: QKV. cols <2048 -> bf16 qk[row][col] (ld 2048); cols >=2048 -> bf16 vT[b,dg,t]
// MODE 1: out f32  = resid + C + bias    (proj)
// MODE 2: out bf16 = gelu(C + bias)      (FC)
// MODE 3: out f32  = resid + C + bias    (FC2)
template <int MODE>
__global__ __launch_bounds__(256) void gemm_bt(const __hip_bfloat16* __restrict__ A,
                                               const __hip_bfloat16* __restrict__ BT,
                                               const float* __restrict__ bias,
                                               const float* __restrict__ resid,
                                               void* __restrict__ outp,
                                               void* __restrict__ outp2,
                                               int N, int K) {
  __shared__ __hip_bfloat16 Als[128 * 64];
  __shared__ __hip_bfloat16 Bls[128 * 64];
  const int tid = threadIdx.x;
  const int w = tid >> 6, l = tid & 63;
  const int tile_n = blockIdx.x * 128;
  const int tile_m = blockIdx.y * 128;
  const int wm = (w >> 1) * 64, wn = (w & 1) * 64;

  f32x4 acc[4][4] = {};

  const int lrow8 = l >> 3;            // 0..7 row within 8-row staging group
  const int gchunk = (l & 7) ^ lrow8;  // which global 16B chunk this lane fetches
  const int m_ = (l & 15);
  const int q_ = (l >> 4);             // 0..3

  for (int k0 = 0; k0 < K; k0 += 64) {
    #pragma unroll
    for (int jj = 0; jj < 2; jj++) {
      const int r0 = w*16 + 8*jj + lrow8;
      __builtin_amdgcn_global_load_lds(GLB_AS(A  + (size_t)(tile_m + r0) * K + k0 + gchunk*8),
                                       LDS_AS(&Als[(w*16 + 8*jj) * 64]), 16, 0, 0);
      __builtin_amdgcn_global_load_lds(GLB_AS(A  + (size_t)(tile_m + 64 + r0) * K + k0 + gchunk*8),
                                       LDS_AS(&Als[(64 + w*16 + 8*jj) * 64]), 16, 0, 0);
      __builtin_amdgcn_global_load_lds(GLB_AS(BT + (size_t)(tile_n + r0) * K + k0 + gchunk*8),
                                       LDS_AS(&Bls[(w*16 + 8*jj) * 64]), 16, 0, 0);
      __builtin_amdgcn_global_load_lds(GLB_AS(BT + (size_t)(tile_n + 64 + r0) * K + k0 + gchunk*8),
                                       LDS_AS(&Bls[(64 + w*16 + 8*jj) * 64]), 16, 0, 0);
    }
    __syncthreads();
    bf16x8 af[2][4], bfr[2][4];
    #pragma unroll
    for (int c = 0; c < 2; c++) {
      #pragma unroll
      for (int mi = 0; mi < 4; mi++) {
        const int row = wm + mi*16 + m_;
        af[c][mi] = *(const bf16x8*)&Als[row * 64 + (((c*4 + q_) ^ (row & 7)) * 8)];
      }
      #pragma unroll
      for (int ni = 0; ni < 4; ni++) {
        const int row = wn + ni*16 + m_;
        bfr[c][ni] = *(const bf16x8*)&Bls[row * 64 + (((c*4 + q_) ^ (row & 7)) * 8)];
      }
    }
    #pragma unroll
    for (int c = 0; c < 2; c++)
      #pragma unroll
      for (int mi = 0; mi < 4; mi++)
        #pragma unroll
        for (int ni = 0; ni < 4; ni++)
          acc[mi][ni] = mfma16(af[c][mi], bfr[c][ni], acc[mi][ni]);
    __syncthreads();
  }

  // epilogue: C/D layout col=lane&15, row=(lane>>4)*4+reg
  const int r0 = tile_m + wm + q_ * 4;
  const int c0 = tile_n + wn + m_;
  #pragma unroll
  for (int mi = 0; mi < 4; mi++) {
    #pragma unroll
    for (int r = 0; r < 4; r++) {
      const int row = r0 + mi * 16 + r;
      #pragma unroll
      for (int ni = 0; ni < 4; ni++) {
        const int col = c0 + ni * 16;
        float v = acc[mi][ni][r] + bias[col];
        if (MODE == 0) {
          if (tile_n < 2 * C_) {
            ((__hip_bfloat16*)outp)[(size_t)row * (2*C_) + col] = f2bf(v);
          } else {
            // vT[(b*1024 + dg)][t], dg = col-2048, b = row>>11, t = row&2047
            const int dg = col - 2 * C_;
            ((__hip_bfloat16*)outp2)[((size_t)((row >> 11) * 1024 + dg)) * T_ + (row & 2047)] = f2bf(v);
          }
        } else if (MODE == 1 || MODE == 3) {
          ((float*)outp)[(size_t)row * N + col] = resid[(size_t)row * N + col] + v;
        } else { // gelu
          const float u = 0.7978845608028654f * (v + 0.044715f * v * v * v);
          const float e = __expf(2.0f * u);
          ((__hip_bfloat16*)outp)[(size_t)row * N + col] = f2bf(v * (1.0f - 1.0f / (e + 1.0f)));
        }
      }
    }
  }
}

// ---------------- flash attention v7 (causal) ----------------
// v6 -> v7: fix the two latency killers seen in rocprof (WRITE_SIZE 73MB vs
// 16MB ideal = ~57MB/dispatch of scratch spills from the 190-reg K/V double
// buffer; grid 512 = 2 blocks/CU).
//  * each wave owns 16 q-rows (1 m-frag), block owns a 64-row HALF of a
//    128-row q-tile -> grid 1024 (64bh x 8 pairs x 2 halves) = 4 blocks/CU
//    = 4 waves/SIMD. TLP replaces the register double-buffer for latency
//    hiding; single-buffered K/V state fits 128 VGPR with no spills.
//  * 64-row half == one 64-col k-tile, so the diagonal (masked) tile is
//    exactly kt==ktlast; half 0 skips its fully-masked tile (32 vs 34 iters,
//    pairing p/(15-p) keeps blocks balanced).
// qk: [B*T][2C] bf16 (Q cols 0..1023, K cols 1024..2047); vT: [B*NH*64][T] bf16
__global__ __launch_bounds__(256, 4) void flash_attn(const __hip_bfloat16* __restrict__ qk,
                                                     const __hip_bfloat16* __restrict__ vT,
                                                     __hip_bfloat16* __restrict__ y) {
  const int id  = blockIdx.x;          // 0..1023
  const int xcd = id & 7;
  const int jj  = id >> 3;             // 0..127
  const int bh  = xcd * 8 + (jj >> 4); // 8 bh per XCD
  const int p   = (jj >> 1) & 7;       // pair index: units qt=p and qt=15-p
  const int half= jj & 1;              // which 64-row half of the 128-row q-tile
  const int b   = bh >> 4, h = bh & 15;
  const int tid = threadIdx.x, w = tid >> 6, l = tid & 63;
  const int m_ = l & 15, q_ = l >> 4;

  __shared__ __hip_bfloat16 Pls[64 * 76];   // 4 waves x 16 wave-local rows, stride 76

  const size_t kgbase = (size_t)b * T_ * (2*C_) + C_ + h*64;  // + t*(2C) + d
  const size_t vgbase = (size_t)bh * 64 * T_;                 // + d*T + t

  #pragma unroll 1
  for (int ui = 0; ui < 2; ui++) {
    const int qt = ui ? (15 - p) : p;
    const int q0 = qt * 128 + half * 64;

    // --- Q fragment (A layout): 1 m-frag x 2 k-halves, scaled by 1/8*log2(e) ---
    bf16x8 aq[2];
    {
      const float qscale = 0.125f * 1.44269504088896f;
      const size_t qbase = ((size_t)b * T_ + q0 + w*16 + m_) * (2*C_) + h*64;
      #pragma unroll
      for (int kh = 0; kh < 2; kh++) {
        union { uint4 u; __hip_bfloat16 h8[8]; } t;
        t.u = *(const uint4*)&qk[qbase + kh*32 + q_*8];
        __hip_bfloat16 a[8];
        #pragma unroll
        for (int jx = 0; jx < 8; jx++) a[jx] = f2bf(bf2f(t.h8[jx]) * qscale);
        aq[kh] = *(const bf16x8*)a;
      }
    }

    f32x4 accO[4] = {};
    float lsum[4] = {0.f, 0.f, 0.f, 0.f};
    const int ktlast = 2*qt + half;     // diagonal tile index (q0 == ktlast*64)

    #pragma unroll 1
    for (int kt = 0; kt <= ktlast; kt++) {
      // --- K/V tile loads (single-buffered; V latency hides under QK+softmax,
      //     inter-iteration latency hidden by 4 waves/SIMD) ---
      bf16x8 bk[4][2], bv[4][2];
      #pragma unroll
      for (int ni = 0; ni < 4; ni++) {
        const __hip_bfloat16* kp = qk + kgbase + (size_t)(kt*64 + ni*16 + m_)*(2*C_);
        union { uint4 u; bf16x8 f; } t0, t1;
        t0.u = *(const uint4*)(kp + q_*8);
        t1.u = *(const uint4*)(kp + 32 + q_*8);
        bk[ni][0] = t0.f; bk[ni][1] = t1.f;
      }
      #pragma unroll
      for (int ni = 0; ni < 4; ni++) {
        const __hip_bfloat16* vp = vT + vgbase + (size_t)(ni*16 + m_)*T_ + kt*64;
        union { uint4 u; bf16x8 f; } t2, t3;
        t2.u = *(const uint4*)(vp + q_*8);
        t3.u = *(const uint4*)(vp + 32 + q_*8);
        bv[ni][0] = t2.f; bv[ni][1] = t3.f;
      }

      // --- QK^T ---
      f32x4 s[4];
      #pragma unroll
      for (int ni = 0; ni < 4; ni++) {
        f32x4 z = {};
        z = mfma16(aq[0], bk[ni][0], z);
        s[ni] = mfma16(aq[1], bk[ni][1], z);
      }

      // --- causal mask: only the diagonal tile needs it ---
      if (kt == ktlast) {
        const int qrow = q0 + w*16 + q_*4;
        #pragma unroll
        for (int ni = 0; ni < 4; ni++) {
          const int kcol = kt*64 + ni*16 + m_;
          #pragma unroll
          for (int r = 0; r < 4; r++)
            if (kcol > qrow + r) s[ni][r] = -1e30f;
        }
      }

      // --- fixed-max exp2 softmax, wave-local P round-trip through LDS ---
      #pragma unroll
      for (int ni = 0; ni < 4; ni++)
        #pragma unroll
        for (int r = 0; r < 4; r++)
          s[ni][r] = exp2f(s[ni][r]);
      #pragma unroll
      for (int r = 0; r < 4; r++)
        lsum[r] += (s[0][r] + s[1][r]) + (s[2][r] + s[3][r]);
      #pragma unroll
      for (int ni = 0; ni < 4; ni++)
        #pragma unroll
        for (int r = 0; r < 4; r++)
          Pls[(w*16 + q_*4 + r) * 76 + ni*16 + m_] = f2bf(s[ni][r]);

      bf16x8 ap[2];
      ap[0] = *(const bf16x8*)&Pls[(w*16 + m_) * 76 + q_*8];
      ap[1] = *(const bf16x8*)&Pls[(w*16 + m_) * 76 + 32 + q_*8];

      // --- PV ---
      #pragma unroll
      for (int ni = 0; ni < 4; ni++) {
        accO[ni] = mfma16(ap[0], bv[ni][0], accO[ni]);
        accO[ni] = mfma16(ap[1], bv[ni][1], accO[ni]);
      }
    }

    // --- epilogue: reduce Sum(p) across the 16 lanes sharing each row, store O/l ---
    #pragma unroll
    for (int r = 0; r < 4; r++) {
      #pragma unroll
      for (int d = 1; d < 16; d <<= 1)
        lsum[r] += __shfl_xor(lsum[r], d, 64);
    }

    const size_t ybase = ((size_t)b * T_ + q0) * C_ + h*64;
    #pragma unroll
    for (int r = 0; r < 4; r++) {
      const int row = w*16 + q_*4 + r;
      const float linv = 1.0f / lsum[r];
      #pragma unroll
      for (int ni = 0; ni < 4; ni++)
        y[ybase + (size_t)row * C_ + ni*16 + m_] = f2bf(accO[ni][r] * linv);
    }
  }
}

// ---------------- launch ----------------
extern "C" void kernel_launch(void* const* d_in, const int* in_sizes, int n_in,
                              void* d_out, int out_size, void* d_ws, size_t ws_size,
                              hipStream_t stream) {
  const float* x      = (const float*)d_in[0];
  const float* ln1_g  = (const float*)d_in[1];
  const float* ln1_b  = (const float*)d_in[2];
  const float* w_attn = (const float*)d_in[3];
  const float* b_attn = (const float*)d_in[4];
  const float* w_proj = (const float*)d_in[5];
  const float* b_proj = (const float*)d_in[6];
  const float* ln2_g  = (const float*)d_in[7];
  const float* ln2_b  = (const float*)d_in[8];
  const float* w_fc   = (const float*)d_in[9];
  const float* b_fc   = (const float*)d_in[10];
  const float* w_fc2  = (const float*)d_in[11];
  const float* b_fc2  = (const float*)d_in[12];
  float* out = (float*)d_out;

  char* ws = (char*)d_ws;
  const size_t MB = 1024 * 1024;
  __hip_bfloat16* h      = (__hip_bfloat16*)(ws);                 // 16MB [0,16)
  __hip_bfloat16* qk     = (__hip_bfloat16*)(ws + 16*MB);         // 32MB [16,48)
  __hip_bfloat16* vT     = (__hip_bfloat16*)(ws + 48*MB);         // 16MB [48,64)
  __hip_bfloat16* y      = (__hip_bfloat16*)(ws + 64*MB);         // 16MB [64,80)
  float*          x2     = (float*)        (ws + 80*MB);          // 32MB [80,112)
  __hip_bfloat16* h2     = (__hip_bfloat16*)(ws + 64*MB);         // reuse y slot
  __hip_bfloat16* gbuf   = (__hip_bfloat16*)(ws);                 // 64MB reuse [0,64)
  __hip_bfloat16* wattnT = (__hip_bfloat16*)(ws + 112*MB);        // 6MB
  __hip_bfloat16* wprojT = (__hip_bfloat16*)(ws + 118*MB);        // 2MB
  __hip_bfloat16* wfcT   = (__hip_bfloat16*)(ws + 120*MB);        // 8MB
  __hip_bfloat16* wfc2T  = (__hip_bfloat16*)(ws + 128*MB);        // 8MB

  // weights: [K][N] fp32 -> [N][K] bf16
  transpose_bf16<<<dim3(3*C_/32, C_/32), 256, 0, stream>>>(w_attn, wattnT, C_, 3*C_);
  transpose_bf16<<<dim3(C_/32,  C_/32), 256, 0, stream>>>(w_proj, wprojT, C_, C_);
  transpose_bf16<<<dim3(FF_/32, C_/32), 256, 0, stream>>>(w_fc,   wfcT,   C_, FF_);
  transpose_bf16<<<dim3(C_/32, FF_/32), 256, 0, stream>>>(w_fc2,  wfc2T,  FF_, C_);

  // LN1
  ln_bf16<<<NT_, 256, 0, stream>>>(x, ln1_g, ln1_b, h);
  // QKV (Q,K -> qk packed [t][2C]; V -> vT [b*1024+dg][t])
  gemm_bt<0><<<dim3(3*C_/128, NT_/128), 256, 0, stream>>>(h, wattnT, b_attn, nullptr, qk, vT, 3*C_, C_);
  // attention (1024 half-tile blocks, 4 blocks/CU)
  flash_attn<<<dim3(1024), 256, 0, stream>>>(qk, vT, y);
  // proj + residual -> x2 (fp32)
  gemm_bt<1><<<dim3(C_/128, NT_/128), 256, 0, stream>>>(y, wprojT, b_proj, x, x2, nullptr, C_, C_);
  // LN2
  ln_bf16<<<NT_, 256, 0, stream>>>(x2, ln2_g, ln2_b, h2);
  // FC + gelu
  gemm_bt<2><<<dim3(FF_/128, NT_/128), 256, 0, stream>>>(h2, wfcT, b_fc, nullptr, gbuf, nullptr, FF_, C_);
  // FC2 + residual -> out (fp32)
  gemm_bt<3><<<dim3(C_/128, NT_/128), 256, 0, stream>>>(gbuf, wfc2T, b_fc2, x2, out, nullptr, C_, FF_);
}

// Round 2
// 537.950 us; speedup vs baseline: 1.3200x; 1.3200x over previous
//
#include <hip/hip_runtime.h>
#include <hip/hip_bf16.h>

#define B_ 4
#define T_ 2048
#define C_ 1024
#define NH_ 16
#define FF_ 4096
#define NT_ (B_*T_)   // 8192 token rows

typedef short bf16x8 __attribute__((ext_vector_type(8)));
typedef float f32x4 __attribute__((ext_vector_type(4)));

#define LDS_AS(p) ((__attribute__((address_space(3))) uint32_t*)(p))
#define GLB_AS(p) ((const __attribute__((address_space(1))) uint32_t*)(p))

__device__ __forceinline__ float bf2f(__hip_bfloat16 v){ return __bfloat162float(v); }
__device__ __forceinline__ __hip_bfloat16 f2bf(float f){ return __float2bfloat16(f); }

__device__ __forceinline__ f32x4 mfma16(bf16x8 a, bf16x8 b, f32x4 c){
  return __builtin_amdgcn_mfma_f32_16x16x32_bf16(a, b, c, 0, 0, 0);
}

// ---------------- weight transpose + fp32->bf16 cast:  in[K][N] -> out[N][K] ----------------
__global__ __launch_bounds__(256) void transpose_bf16(const float* __restrict__ in,
                                                      __hip_bfloat16* __restrict__ out,
                                                      int K, int N) {
  __shared__ float tile[32][33];
  const int n0 = blockIdx.x * 32, k0 = blockIdx.y * 32;
  const int x = threadIdx.x & 31, y = threadIdx.x >> 5;   // y in 0..7
  #pragma unroll
  for (int i = 0; i < 4; i++)
    tile[y + 8*i][x] = in[(size_t)(k0 + y + 8*i) * N + n0 + x];
  __syncthreads();
  #pragma unroll
  for (int i = 0; i < 4; i++)
    out[(size_t)(n0 + y + 8*i) * K + k0 + x] = f2bf(tile[x][y + 8*i]);
}

// ---------------- LayerNorm fp32 -> bf16 (row = 1024) ----------------
__global__ __launch_bounds__(256) void ln_bf16(const float* __restrict__ x,
                                               const float* __restrict__ g,
                                               const float* __restrict__ b,
                                               __hip_bfloat16* __restrict__ out) {
  const int row = blockIdx.x;
  const int tid = threadIdx.x;
  float4 v = ((const float4*)(x + (size_t)row * C_))[tid];
  float s  = v.x + v.y + v.z + v.w;
  float s2 = v.x*v.x + v.y*v.y + v.z*v.z + v.w*v.w;
  #pragma unroll
  for (int off = 32; off > 0; off >>= 1) {
    s  += __shfl_down(s,  off, 64);
    s2 += __shfl_down(s2, off, 64);
  }
  __shared__ float red[8];
  const int w = tid >> 6, l = tid & 63;
  if (l == 0) { red[w] = s; red[4 + w] = s2; }
  __syncthreads();
  s  = red[0] + red[1] + red[2] + red[3];
  s2 = red[4] + red[5] + red[6] + red[7];
  const float mu   = s * (1.0f / C_);
  const float var  = s2 * (1.0f / C_) - mu * mu;
  const float rstd = rsqrtf(var + 1e-5f);
  float4 gv = ((const float4*)g)[tid];
  float4 bv = ((const float4*)b)[tid];
  ushort4 o;
  __hip_bfloat16 t;
  t = f2bf((v.x - mu) * rstd * gv.x + bv.x); o.x = *(unsigned short*)&t;
  t = f2bf((v.y - mu) * rstd * gv.y + bv.y); o.y = *(unsigned short*)&t;
  t = f2bf((v.z - mu) * rstd * gv.z + bv.z); o.z = *(unsigned short*)&t;
  t = f2bf((v.w - mu) * rstd * gv.w + bv.w); o.w = *(unsigned short*)&t;
  ((ushort4*)out)[(size_t)row * (C_/4) + tid] = o;
}

// ---------------- shared MFMA GEMM, BK=64, XOR-swizzled staging ----------------
// C[M][N] = A[M][K] * BT[N][K]^T + epilogue
// MODE 0: QKV. cols <2048 -> bf16 qk[row][col] (ld 2048); cols >=2048 -> bf16 vT[b,dg,t]
// MODE 1: out f32  = resid + C + bias    (proj)
// MODE 2: out bf16 = gelu(C + bias)      (FC)
// MODE 3: out f32  = resid + C + bias    (FC2)
template <int MODE>
__global__ __launch_bounds__(256) void gemm_bt(const __hip_bfloat16* __restrict__ A,
                                               const __hip_bfloat16* __restrict__ BT,
                                               const float* __restrict__ bias,
                                               const float* __restrict__ resid,
                                               void* __restrict__ outp,
                                               void* __restrict__ outp2,
                                               int N, int K) {
  __shared__ __hip_bfloat16 Als[128 * 64];
  __shared__ __hip_bfloat16 Bls[128 * 64];
  const int tid = threadIdx.x;
  const int w = tid >> 6, l = tid & 63;
  const int tile_n = blockIdx.x * 128;
  const int tile_m = blockIdx.y * 128;
  const int wm = (w >> 1) * 64, wn = (w & 1) * 64;

  f32x4 acc[4][4] = {};

  const int lrow8 = l >> 3;            // 0..7 row within 8-row staging group
  const int gchunk = (l & 7) ^ lrow8;  // which global 16B chunk this lane fetches
  const int m_ = (l & 15);
  const int q_ = (l >> 4);             // 0..3

  for (int k0 = 0; k0 < K; k0 += 64) {
    #pragma unroll
    for (int jj = 0; jj < 2; jj++) {
      const int r0 = w*16 + 8*jj + lrow8;
      __builtin_amdgcn_global_load_lds(GLB_AS(A  + (size_t)(tile_m + r0) * K + k0 + gchunk*8),
                                       LDS_AS(&Als[(w*16 + 8*jj) * 64]), 16, 0, 0);
      __builtin_amdgcn_global_load_lds(GLB_AS(A  + (size_t)(tile_m + 64 + r0) * K + k0 + gchunk*8),
                                       LDS_AS(&Als[(64 + w*16 + 8*jj) * 64]), 16, 0, 0);
      __builtin_amdgcn_global_load_lds(GLB_AS(BT + (size_t)(tile_n + r0) * K + k0 + gchunk*8),
                                       LDS_AS(&Bls[(w*16 + 8*jj) * 64]), 16, 0, 0);
      __builtin_amdgcn_global_load_lds(GLB_AS(BT + (size_t)(tile_n + 64 + r0) * K + k0 + gchunk*8),
                                       LDS_AS(&Bls[(64 + w*16 + 8*jj) * 64]), 16, 0, 0);
    }
    __syncthreads();
    bf16x8 af[2][4], bfr[2][4];
    #pragma unroll
    for (int c = 0; c < 2; c++) {
      #pragma unroll
      for (int mi = 0; mi < 4; mi++) {
        const int row = wm + mi*16 + m_;
        af[c][mi] = *(const bf16x8*)&Als[row * 64 + (((c*4 + q_) ^ (row & 7)) * 8)];
      }
      #pragma unroll
      for (int ni = 0; ni < 4; ni++) {
        const int row = wn + ni*16 + m_;
        bfr[c][ni] = *(const bf16x8*)&Bls[row * 64 + (((c*4 + q_) ^ (row & 7)) * 8)];
      }
    }
    #pragma unroll
    for (int c = 0; c < 2; c++)
      #pragma unroll
      for (int mi = 0; mi < 4; mi++)
        #pragma unroll
        for (int ni = 0; ni < 4; ni++)
          acc[mi][ni] = mfma16(af[c][mi], bfr[c][ni], acc[mi][ni]);
    __syncthreads();
  }

  // epilogue: C/D layout col=lane&15, row=(lane>>4)*4+reg
  const int r0 = tile_m + wm + q_ * 4;
  const int c0 = tile_n + wn + m_;
  #pragma unroll
  for (int mi = 0; mi < 4; mi++) {
    #pragma unroll
    for (int r = 0; r < 4; r++) {
      const int row = r0 + mi * 16 + r;
      #pragma unroll
      for (int ni = 0; ni < 4; ni++) {
        const int col = c0 + ni * 16;
        float v = acc[mi][ni][r] + bias[col];
        if (MODE == 0) {
          if (tile_n < 2 * C_) {
            ((__hip_bfloat16*)outp)[(size_t)row * (2*C_) + col] = f2bf(v);
          } else {
            // vT[(b*1024 + dg)][t], dg = col-2048, b = row>>11, t = row&2047
            const int dg = col - 2 * C_;
            ((__hip_bfloat16*)outp2)[((size_t)((row >> 11) * 1024 + dg)) * T_ + (row & 2047)] = f2bf(v);
          }
        } else if (MODE == 1 || MODE == 3) {
          ((float*)outp)[(size_t)row * N + col] = resid[(size_t)row * N + col] + v;
        } else { // gelu
          const float u = 0.7978845608028654f * (v + 0.044715f * v * v * v);
          const float e = __expf(2.0f * u);
          ((__hip_bfloat16*)outp)[(size_t)row * N + col] = f2bf(v * (1.0f - 1.0f / (e + 1.0f)));
        }
      }
    }
  }
}

// ---------------- flash attention v8 (causal) ----------------
// v7 -> v8: v7's per-lane K/V register loads serialized (VGPR=56, load->use
// chains of full L2 latency per iteration; MfmaUtil 5.6%). v8 stages K/V via
// global_load_lds (no VGPR cost for in-flight data), K double-buffered,
// counted vmcnt so next-tile K loads stay in flight across the barrier (T3/T4),
// all 4 waves share each staged tile (4x fewer global ops).
//  * block = 4 waves x 16 q-rows = 64-row q-tile; k-tile 64 -> diagonal at
//    kt==qt; pairing qt=p / 31-p gives every block exactly 33 iterations.
//    grid 1024 = 64bh x 16 pairs = exactly 4 blocks/CU, uniform, no tail.
//  * LDS: K dbuf 16KB + V 8KB + Pls 9.5KB = 34.3KB -> 4 blocks/CU.
//  * K/V tiles use the GEMM's XOR-chunk swizzle (0 conflicts measured there);
//    Pls stride 76 (0 conflicts measured).
// qk: [B*T][2C] bf16 (Q cols 0..1023, K cols 1024..2047); vT: [B*NH*64][T] bf16
__global__ __launch_bounds__(256, 4) void flash_attn(const __hip_bfloat16* __restrict__ qk,
                                                     const __hip_bfloat16* __restrict__ vT,
                                                     __hip_bfloat16* __restrict__ y) {
  const int id  = blockIdx.x;          // 0..1023
  const int xcd = id & 7;
  const int jj  = id >> 3;             // 0..127
  const int bh  = xcd * 8 + (jj >> 4); // 8 bh per XCD
  const int p   = jj & 15;             // pair: qt=p and qt=31-p (64-row q-tiles)
  const int b   = bh >> 4, h = bh & 15;
  const int tid = threadIdx.x, w = tid >> 6, l = tid & 63;
  const int m_ = l & 15, q_ = l >> 4;
  const int lrow8 = l >> 3;            // 0..7 row within 8-row staging group
  const int gchunk = (l & 7) ^ lrow8;  // global 16B chunk this lane fetches

  __shared__ __hip_bfloat16 Kls[2][64 * 64];  // 16KB double-buffered K tile
  __shared__ __hip_bfloat16 Vls[64 * 64];     // 8KB V tile
  __shared__ __hip_bfloat16 Pls[64 * 76];     // 9.5KB wave-local P bands

  const size_t kgbase = (size_t)b * T_ * (2*C_) + C_ + h*64;  // + t*(2C) + d
  const size_t vgbase = (size_t)bh * 64 * T_;                 // + d*T + t

  // stage a 64x64 bf16 tile (8KB): 2 global_load_lds per thread, 8-row groups,
  // LDS linear dest, XOR-preswizzled global source (slot s of row r holds
  // global chunk s^(r&7))
#define STAGE_K(kt_, buf_) do {                                                        \
    _Pragma("unroll")                                                                  \
    for (int j2 = 0; j2 < 2; j2++) {                                                   \
      const int rg = j2*32 + w*8;                                                      \
      __builtin_amdgcn_global_load_lds(                                                \
        GLB_AS(qk + kgbase + (size_t)((kt_)*64 + rg + lrow8)*(2*C_) + gchunk*8),       \
        LDS_AS(&Kls[buf_][rg*64]), 16, 0, 0);                                          \
    }                                                                                  \
  } while (0)

#define STAGE_V(kt_) do {                                                              \
    _Pragma("unroll")                                                                  \
    for (int j2 = 0; j2 < 2; j2++) {                                                   \
      const int rg = j2*32 + w*8;                                                      \
      __builtin_amdgcn_global_load_lds(                                                \
        GLB_AS(vT + vgbase + (size_t)(rg + lrow8)*T_ + (kt_)*64 + gchunk*8),           \
        LDS_AS(&Vls[rg*64]), 16, 0, 0);                                                \
    }                                                                                  \
  } while (0)

  #pragma unroll 1
  for (int ui = 0; ui < 2; ui++) {
    const int qt = ui ? (31 - p) : p;
    const int q0 = qt * 64;

    // --- Q fragment (A layout): 16 rows/wave, scaled by 1/8*log2(e) ---
    bf16x8 aq[2];
    {
      const float qscale = 0.125f * 1.44269504088896f;
      const size_t qbase = ((size_t)b * T_ + q0 + w*16 + m_) * (2*C_) + h*64;
      #pragma unroll
      for (int kh = 0; kh < 2; kh++) {
        union { uint4 u; __hip_bfloat16 h8[8]; } t;
        t.u = *(const uint4*)&qk[qbase + kh*32 + q_*8];
        __hip_bfloat16 a[8];
        #pragma unroll
        for (int jx = 0; jx < 8; jx++) a[jx] = f2bf(bf2f(t.h8[jx]) * qscale);
        aq[kh] = *(const bf16x8*)a;
      }
    }

    f32x4 accO[4] = {};
    float lsum[4] = {0.f, 0.f, 0.f, 0.f};

    // prologue: stage K[0]
    STAGE_K(0, 0);
    asm volatile("s_waitcnt vmcnt(0)" ::: "memory");
    __builtin_amdgcn_s_barrier();

    int cur = 0;
    #pragma unroll 1
    for (int kt = 0; kt <= qt; kt++) {
      // issue V[kt] staging; latency hides under QK^T + softmax
      STAGE_V(kt);

      // --- QK^T from LDS (B-fragment reads, XOR-swizzled: conflict-free) ---
      f32x4 s[4];
      #pragma unroll
      for (int ni = 0; ni < 4; ni++) {
        const int row = ni*16 + m_;
        const bf16x8 bk0 = *(const bf16x8*)&Kls[cur][row*64 + ((q_     ^ (row & 7)) * 8)];
        const bf16x8 bk1 = *(const bf16x8*)&Kls[cur][row*64 + (((4+q_) ^ (row & 7)) * 8)];
        f32x4 z = {};
        z = mfma16(aq[0], bk0, z);
        s[ni] = mfma16(aq[1], bk1, z);
      }

      // issue next K tile; stays in flight across the counted-vmcnt barrier
      if (kt < qt) STAGE_K(kt + 1, cur ^ 1);

      // --- causal mask: only the diagonal tile ---
      if (kt == qt) {
        const int qrow = w*16 + q_*4;
        #pragma unroll
        for (int ni = 0; ni < 4; ni++) {
          const int kcol = ni*16 + m_;
          #pragma unroll
          for (int r = 0; r < 4; r++)
            if (kcol > qrow + r) s[ni][r] = -1e30f;
        }
      }

      // --- fixed-max exp2 softmax, wave-local P round-trip through LDS ---
      #pragma unroll
      for (int ni = 0; ni < 4; ni++)
        #pragma unroll
        for (int r = 0; r < 4; r++)
          s[ni][r] = exp2f(s[ni][r]);
      #pragma unroll
      for (int r = 0; r < 4; r++)
        lsum[r] += (s[0][r] + s[1][r]) + (s[2][r] + s[3][r]);
      #pragma unroll
      for (int ni = 0; ni < 4; ni++)
        #pragma unroll
        for (int r = 0; r < 4; r++)
          Pls[(w*16 + q_*4 + r) * 76 + ni*16 + m_] = f2bf(s[ni][r]);

      bf16x8 ap[2];
      ap[0] = *(const bf16x8*)&Pls[(w*16 + m_) * 76 + q_*8];
      ap[1] = *(const bf16x8*)&Pls[(w*16 + m_) * 76 + 32 + q_*8];

      // V landed (2 oldest); next-K (2 newest) stays in flight
      if (kt < qt) asm volatile("s_waitcnt vmcnt(2)" ::: "memory");
      else         asm volatile("s_waitcnt vmcnt(0)" ::: "memory");
      __builtin_amdgcn_s_barrier();

      // --- PV from LDS ---
      #pragma unroll
      for (int ni = 0; ni < 4; ni++) {
        const int row = ni*16 + m_;
        const bf16x8 bv0 = *(const bf16x8*)&Vls[row*64 + ((q_     ^ (row & 7)) * 8)];
        const bf16x8 bv1 = *(const bf16x8*)&Vls[row*64 + (((4+q_) ^ (row & 7)) * 8)];
        accO[ni] = mfma16(ap[0], bv0, accO[ni]);
        accO[ni] = mfma16(ap[1], bv1, accO[ni]);
      }

      // next K fully landed + all our LDS reads retired, then handoff barrier
      asm volatile("s_waitcnt vmcnt(0) lgkmcnt(0)" ::: "memory");
      __builtin_amdgcn_s_barrier();
      cur ^= 1;
    }

    // --- epilogue: reduce Sum(p) across the 16 lanes sharing each row, store O/l ---
    #pragma unroll
    for (int r = 0; r < 4; r++) {
      #pragma unroll
      for (int d = 1; d < 16; d <<= 1)
        lsum[r] += __shfl_xor(lsum[r], d, 64);
    }

    const size_t ybase = ((size_t)b * T_ + q0) * C_ + h*64;
    #pragma unroll
    for (int r = 0; r < 4; r++) {
      const int row = w*16 + q_*4 + r;
      const float linv = 1.0f / lsum[r];
      #pragma unroll
      for (int ni = 0; ni < 4; ni++)
        y[ybase + (size_t)row * C_ + ni*16 + m_] = f2bf(accO[ni][r] * linv);
    }
  }
#undef STAGE_K
#undef STAGE_V
}

// ---------------- launch ----------------
extern "C" void kernel_launch(void* const* d_in, const int* in_sizes, int n_in,
                              void* d_out, int out_size, void* d_ws, size_t ws_size,
                              hipStream_t stream) {
  const float* x      = (const float*)d_in[0];
  const float* ln1_g  = (const float*)d_in[1];
  const float* ln1_b  = (const float*)d_in[2];
  const float* w_attn = (const float*)d_in[3];
  const float* b_attn = (const float*)d_in[4];
  const float* w_proj = (const float*)d_in[5];
  const float* b_proj = (const float*)d_in[6];
  const float* ln2_g  = (const float*)d_in[7];
  const float* ln2_b  = (const float*)d_in[8];
  const float* w_fc   = (const float*)d_in[9];
  const float* b_fc   = (const float*)d_in[10];
  const float* w_fc2  = (const float*)d_in[11];
  const float* b_fc2  = (const float*)d_in[12];
  float* out = (float*)d_out;

  char* ws = (char*)d_ws;
  const size_t MB = 1024 * 1024;
  __hip_bfloat16* h      = (__hip_bfloat16*)(ws);                 // 16MB [0,16)
  __hip_bfloat16* qk     = (__hip_bfloat16*)(ws + 16*MB);         // 32MB [16,48)
  __hip_bfloat16* vT     = (__hip_bfloat16*)(ws + 48*MB);         // 16MB [48,64)
  __hip_bfloat16* y      = (__hip_bfloat16*)(ws + 64*MB);         // 16MB [64,80)
  float*          x2     = (float*)        (ws + 80*MB);          // 32MB [80,112)
  __hip_bfloat16* h2     = (__hip_bfloat16*)(ws + 64*MB);         // reuse y slot
  __hip_bfloat16* gbuf   = (__hip_bfloat16*)(ws);                 // 64MB reuse [0,64)
  __hip_bfloat16* wattnT = (__hip_bfloat16*)(ws + 112*MB);        // 6MB
  __hip_bfloat16* wprojT = (__hip_bfloat16*)(ws + 118*MB);        // 2MB
  __hip_bfloat16* wfcT   = (__hip_bfloat16*)(ws + 120*MB);        // 8MB
  __hip_bfloat16* wfc2T  = (__hip_bfloat16*)(ws + 128*MB);        // 8MB

  // weights: [K][N] fp32 -> [N][K] bf16
  transpose_bf16<<<dim3(3*C_/32, C_/32), 256, 0, stream>>>(w_attn, wattnT, C_, 3*C_);
  transpose_bf16<<<dim3(C_/32,  C_/32), 256, 0, stream>>>(w_proj, wprojT, C_, C_);
  transpose_bf16<<<dim3(FF_/32, C_/32), 256, 0, stream>>>(w_fc,   wfcT,   C_, FF_);
  transpose_bf16<<<dim3(C_/32, FF_/32), 256, 0, stream>>>(w_fc2,  wfc2T,  FF_, C_);

  // LN1
  ln_bf16<<<NT_, 256, 0, stream>>>(x, ln1_g, ln1_b, h);
  // QKV (Q,K -> qk packed [t][2C]; V -> vT [b*1024+dg][t])
  gemm_bt<0><<<dim3(3*C_/128, NT_/128), 256, 0, stream>>>(h, wattnT, b_attn, nullptr, qk, vT, 3*C_, C_);
  // attention (1024 blocks = 64bh x 16 pairs, 4 blocks/CU, LDS-staged K/V)
  flash_attn<<<dim3(1024), 256, 0, stream>>>(qk, vT, y);
  // proj + residual -> x2 (fp32)
  gemm_bt<1><<<dim3(C_/128, NT_/128), 256, 0, stream>>>(y, wprojT, b_proj, x, x2, nullptr, C_, C_);
  // LN2
  ln_bf16<<<NT_, 256, 0, stream>>>(x2, ln2_g, ln2_b, h2);
  // FC + gelu
  gemm_bt<2><<<dim3(FF_/128, NT_/128), 256, 0, stream>>>(h2, wfcT, b_fc, nullptr, gbuf, nullptr, FF_, C_);
  // FC2 + residual -> out (fp32)
  gemm_bt<3><<<dim3(C_/128, NT_/128), 256, 0, stream>>>(gbuf, wfc2T, b_fc2, x2, out, nullptr, C_, FF_);
}

// Round 3
// 526.175 us; speedup vs baseline: 1.3495x; 1.0224x over previous
//
#include <hip/hip_runtime.h>
#include <hip/hip_bf16.h>

#define B_ 4
#define T_ 2048
#define C_ 1024
#define NH_ 16
#define FF_ 4096
#define NT_ (B_*T_)   // 8192 token rows

typedef short bf16x8 __attribute__((ext_vector_type(8)));
typedef float f32x4 __attribute__((ext_vector_type(4)));

#define LDS_AS(p) ((__attribute__((address_space(3))) uint32_t*)(p))
#define GLB_AS(p) ((const __attribute__((address_space(1))) uint32_t*)(p))

__device__ __forceinline__ float bf2f(__hip_bfloat16 v){ return __bfloat162float(v); }
__device__ __forceinline__ __hip_bfloat16 f2bf(float f){ return __float2bfloat16(f); }

__device__ __forceinline__ f32x4 mfma16(bf16x8 a, bf16x8 b, f32x4 c){
  return __builtin_amdgcn_mfma_f32_16x16x32_bf16(a, b, c, 0, 0, 0);
}

// ---------------- weight transpose + fp32->bf16 cast:  in[K][N] -> out[N][K] ----------------
__global__ __launch_bounds__(256) void transpose_bf16(const float* __restrict__ in,
                                                      __hip_bfloat16* __restrict__ out,
                                                      int K, int N) {
  __shared__ float tile[32][33];
  const int n0 = blockIdx.x * 32, k0 = blockIdx.y * 32;
  const int x = threadIdx.x & 31, y = threadIdx.x >> 5;   // y in 0..7
  #pragma unroll
  for (int i = 0; i < 4; i++)
    tile[y + 8*i][x] = in[(size_t)(k0 + y + 8*i) * N + n0 + x];
  __syncthreads();
  #pragma unroll
  for (int i = 0; i < 4; i++)
    out[(size_t)(n0 + y + 8*i) * K + k0 + x] = f2bf(tile[x][y + 8*i]);
}

// ---------------- LayerNorm fp32 -> bf16 (row = 1024) ----------------
__global__ __launch_bounds__(256) void ln_bf16(const float* __restrict__ x,
                                               const float* __restrict__ g,
                                               const float* __restrict__ b,
                                               __hip_bfloat16* __restrict__ out) {
  const int row = blockIdx.x;
  const int tid = threadIdx.x;
  float4 v = ((const float4*)(x + (size_t)row * C_))[tid];
  float s  = v.x + v.y + v.z + v.w;
  float s2 = v.x*v.x + v.y*v.y + v.z*v.z + v.w*v.w;
  #pragma unroll
  for (int off = 32; off > 0; off >>= 1) {
    s  += __shfl_down(s,  off, 64);
    s2 += __shfl_down(s2, off, 64);
  }
  __shared__ float red[8];
  const int w = tid >> 6, l = tid & 63;
  if (l == 0) { red[w] = s; red[4 + w] = s2; }
  __syncthreads();
  s  = red[0] + red[1] + red[2] + red[3];
  s2 = red[4] + red[5] + red[6] + red[7];
  const float mu   = s * (1.0f / C_);
  const float var  = s2 * (1.0f / C_) - mu * mu;
  const float rstd = rsqrtf(var + 1e-5f);
  float4 gv = ((const float4*)g)[tid];
  float4 bv = ((const float4*)b)[tid];
  ushort4 o;
  __hip_bfloat16 t;
  t = f2bf((v.x - mu) * rstd * gv.x + bv.x); o.x = *(unsigned short*)&t;
  t = f2bf((v.y - mu) * rstd * gv.y + bv.y); o.y = *(unsigned short*)&t;
  t = f2bf((v.z - mu) * rstd * gv.z + bv.z); o.z = *(unsigned short*)&t;
  t = f2bf((v.w - mu) * rstd * gv.w + bv.w); o.w = *(unsigned short*)&t;
  ((ushort4*)out)[(size_t)row * (C_/4) + tid] = o;
}

// ---------------- 256-wide MFMA GEMM v2: double-buffered, wave-owned staging ----------------
// C[M][N] = A[M][K] * BT[N][K]^T + epilogue.  BN=256 fixed, BM template (128/256),
// BK=64, 8 waves (512 thr) as 2(m) x 4(n), per-wave out (BM/2) x 64.
// Pipeline: iter t issues STAGE(tile t+1 -> buf^1) FIRST, then computes tile t
// from buf, then ONE __syncthreads (its vmcnt(0) drain is overlapped by the
// whole compute body since the loads were issued a full tile earlier).
// Wave-owned staging: each wave stages exactly the A-half (rows wm*(BM/2)..)
// and B-half (rows (wn>>1)*128..) that it alone consumes, so its own loads
// land well before its barrier entry.
// LDS slot s of row r holds global 16B chunk s^(r&7) (XOR swizzle, 0 conflicts
// measured); reads use chunk ((kc*4+q_)^(row&7)).
// MODE 0: QKV. cols <2048 -> bf16 qk[row][col] (ld 2048); cols >=2048 -> bf16 vT[b,dg,t]
// MODE 1: out f32  = resid + C + bias    (proj)
// MODE 2: out bf16 = gelu(C + bias)      (FC)
// MODE 3: out f32  = resid + C + bias    (FC2)
template <int MODE, int BM>
__global__ __launch_bounds__(512, 2) void gemm256(const __hip_bfloat16* __restrict__ A,
                                                  const __hip_bfloat16* __restrict__ BT,
                                                  const float* __restrict__ bias,
                                                  const float* __restrict__ resid,
                                                  void* __restrict__ outp,
                                                  void* __restrict__ outp2,
                                                  int N, int K) {
  constexpr int MF = BM / 32;            // per-wave m fragments (4 or 8)
  constexpr int AJ = (BM == 256) ? 4 : 2; // A-stage instrs per thread
  __shared__ __hip_bfloat16 Als[2][BM * 64];
  __shared__ __hip_bfloat16 Bls[2][256 * 64];
  const int tid = threadIdx.x;
  const int w = tid >> 6, l = tid & 63;
  const int wm = w >> 2, wn = w & 3;     // wave grid 2 x 4
  const int m_ = l & 15, q_ = l >> 4;
  const int lrow8 = l >> 3;
  const int gchunk = (l & 7) ^ lrow8;

  // bijective XCD swizzle (all launches have gridDim.x % 8 == 0)
  const int nwg = gridDim.x;
  const int bid = blockIdx.x;
  const int swz = (bid & 7) * (nwg >> 3) + (bid >> 3);
  const int nbx = N >> 8;
  const int tile_n = (swz % nbx) * 256;
  const int tile_m = (swz / nbx) * BM;

  // wave-owned staging row bases
  const int arow0 = (BM == 256) ? (wm * 128 + wn * 32) : (wm * 64 + wn * 16);
  const int brow0 = (wn >> 1) * 128 + (wm * 2 + (wn & 1)) * 32;

  f32x4 acc[MF][4] = {};

#define STAGE256(buf_, k0_) do {                                                   \
    _Pragma("unroll")                                                              \
    for (int j = 0; j < AJ; j++) {                                                 \
      const int rg = arow0 + j*8;                                                  \
      __builtin_amdgcn_global_load_lds(                                            \
        GLB_AS(A + (size_t)(tile_m + rg + lrow8) * K + (k0_) + gchunk*8),          \
        LDS_AS(&Als[buf_][rg*64]), 16, 0, 0);                                      \
    }                                                                              \
    _Pragma("unroll")                                                              \
    for (int j = 0; j < 4; j++) {                                                  \
      const int rg = brow0 + j*8;                                                  \
      __builtin_amdgcn_global_load_lds(                                            \
        GLB_AS(BT + (size_t)(tile_n + rg + lrow8) * K + (k0_) + gchunk*8),         \
        LDS_AS(&Bls[buf_][rg*64]), 16, 0, 0);                                      \
    }                                                                              \
  } while (0)

  // prologue: stage tile 0
  STAGE256(0, 0);
  __syncthreads();

  const int nt = K >> 6;
  int cur = 0;
  #pragma unroll 1
  for (int t = 0; t < nt; t++) {
    // issue next-tile staging first; lands during this tile's compute
    if (t + 1 < nt) STAGE256(cur ^ 1, (t + 1) * 64);

    // B fragments once (reused by all MF m-frags)
    bf16x8 bfr[2][4];
    #pragma unroll
    for (int kc = 0; kc < 2; kc++)
      #pragma unroll
      for (int ni = 0; ni < 4; ni++) {
        const int row = wn*64 + ni*16 + m_;
        bfr[kc][ni] = *(const bf16x8*)&Bls[cur][row*64 + (((kc*4 + q_) ^ (row & 7)) * 8)];
      }
    #pragma unroll
    for (int mi = 0; mi < MF; mi++) {
      const int row = wm*(BM/2) + mi*16 + m_;
      const bf16x8 a0 = *(const bf16x8*)&Als[cur][row*64 + ((q_       ^ (row & 7)) * 8)];
      const bf16x8 a1 = *(const bf16x8*)&Als[cur][row*64 + (((4 + q_) ^ (row & 7)) * 8)];
      #pragma unroll
      for (int ni = 0; ni < 4; ni++) acc[mi][ni] = mfma16(a0, bfr[0][ni], acc[mi][ni]);
      #pragma unroll
      for (int ni = 0; ni < 4; ni++) acc[mi][ni] = mfma16(a1, bfr[1][ni], acc[mi][ni]);
    }
    __syncthreads();   // drains our (long-issued) stage loads; frees buf cur
    cur ^= 1;
  }
#undef STAGE256

  // epilogue: C/D layout col=lane&15, row=(lane>>4)*4+reg
  const int r0 = tile_m + wm * (BM/2) + q_ * 4;
  const int c0 = tile_n + wn * 64 + m_;
  #pragma unroll
  for (int mi = 0; mi < MF; mi++) {
    #pragma unroll
    for (int r = 0; r < 4; r++) {
      const int row = r0 + mi * 16 + r;
      #pragma unroll
      for (int ni = 0; ni < 4; ni++) {
        const int col = c0 + ni * 16;
        float v = acc[mi][ni][r] + bias[col];
        if (MODE == 0) {
          if (tile_n < 2 * C_) {
            ((__hip_bfloat16*)outp)[(size_t)row * (2*C_) + col] = f2bf(v);
          } else {
            // vT[(b*1024 + dg)][t], dg = col-2048, b = row>>11, t = row&2047
            const int dg = col - 2 * C_;
            ((__hip_bfloat16*)outp2)[((size_t)((row >> 11) * 1024 + dg)) * T_ + (row & 2047)] = f2bf(v);
          }
        } else if (MODE == 1 || MODE == 3) {
          ((float*)outp)[(size_t)row * N + col] = resid[(size_t)row * N + col] + v;
        } else { // gelu
          const float u = 0.7978845608028654f * (v + 0.044715f * v * v * v);
          const float e = __expf(2.0f * u);
          ((__hip_bfloat16*)outp)[(size_t)row * N + col] = f2bf(v * (1.0f - 1.0f / (e + 1.0f)));
        }
      }
    }
  }
}

// ---------------- flash attention v8 (causal) ---------------- (unchanged from round 2)
// qk: [B*T][2C] bf16 (Q cols 0..1023, K cols 1024..2047); vT: [B*NH*64][T] bf16
__global__ __launch_bounds__(256, 4) void flash_attn(const __hip_bfloat16* __restrict__ qk,
                                                     const __hip_bfloat16* __restrict__ vT,
                                                     __hip_bfloat16* __restrict__ y) {
  const int id  = blockIdx.x;          // 0..1023
  const int xcd = id & 7;
  const int jj  = id >> 3;             // 0..127
  const int bh  = xcd * 8 + (jj >> 4); // 8 bh per XCD
  const int p   = jj & 15;             // pair: qt=p and qt=31-p (64-row q-tiles)
  const int b   = bh >> 4, h = bh & 15;
  const int tid = threadIdx.x, w = tid >> 6, l = tid & 63;
  const int m_ = l & 15, q_ = l >> 4;
  const int lrow8 = l >> 3;            // 0..7 row within 8-row staging group
  const int gchunk = (l & 7) ^ lrow8;  // global 16B chunk this lane fetches

  __shared__ __hip_bfloat16 Kls[2][64 * 64];  // 16KB double-buffered K tile
  __shared__ __hip_bfloat16 Vls[64 * 64];     // 8KB V tile
  __shared__ __hip_bfloat16 Pls[64 * 76];     // 9.5KB wave-local P bands

  const size_t kgbase = (size_t)b * T_ * (2*C_) + C_ + h*64;  // + t*(2C) + d
  const size_t vgbase = (size_t)bh * 64 * T_;                 // + d*T + t

#define STAGE_K(kt_, buf_) do {                                                        \
    _Pragma("unroll")                                                                  \
    for (int j2 = 0; j2 < 2; j2++) {                                                   \
      const int rg = j2*32 + w*8;                                                      \
      __builtin_amdgcn_global_load_lds(                                                \
        GLB_AS(qk + kgbase + (size_t)((kt_)*64 + rg + lrow8)*(2*C_) + gchunk*8),       \
        LDS_AS(&Kls[buf_][rg*64]), 16, 0, 0);                                          \
    }                                                                                  \
  } while (0)

#define STAGE_V(kt_) do {                                                              \
    _Pragma("unroll")                                                                  \
    for (int j2 = 0; j2 < 2; j2++) {                                                   \
      const int rg = j2*32 + w*8;                                                      \
      __builtin_amdgcn_global_load_lds(                                                \
        GLB_AS(vT + vgbase + (size_t)(rg + lrow8)*T_ + (kt_)*64 + gchunk*8),           \
        LDS_AS(&Vls[rg*64]), 16, 0, 0);                                                \
    }                                                                                  \
  } while (0)

  #pragma unroll 1
  for (int ui = 0; ui < 2; ui++) {
    const int qt = ui ? (31 - p) : p;
    const int q0 = qt * 64;

    // --- Q fragment (A layout): 16 rows/wave, scaled by 1/8*log2(e) ---
    bf16x8 aq[2];
    {
      const float qscale = 0.125f * 1.44269504088896f;
      const size_t qbase = ((size_t)b * T_ + q0 + w*16 + m_) * (2*C_) + h*64;
      #pragma unroll
      for (int kh = 0; kh < 2; kh++) {
        union { uint4 u; __hip_bfloat16 h8[8]; } t;
        t.u = *(const uint4*)&qk[qbase + kh*32 + q_*8];
        __hip_bfloat16 a[8];
        #pragma unroll
        for (int jx = 0; jx < 8; jx++) a[jx] = f2bf(bf2f(t.h8[jx]) * qscale);
        aq[kh] = *(const bf16x8*)a;
      }
    }

    f32x4 accO[4] = {};
    float lsum[4] = {0.f, 0.f, 0.f, 0.f};

    // prologue: stage K[0]
    STAGE_K(0, 0);
    asm volatile("s_waitcnt vmcnt(0)" ::: "memory");
    __builtin_amdgcn_s_barrier();

    int cur = 0;
    #pragma unroll 1
    for (int kt = 0; kt <= qt; kt++) {
      // issue V[kt] staging; latency hides under QK^T + softmax
      STAGE_V(kt);

      // --- QK^T from LDS (B-fragment reads, XOR-swizzled: conflict-free) ---
      f32x4 s[4];
      #pragma unroll
      for (int ni = 0; ni < 4; ni++) {
        const int row = ni*16 + m_;
        const bf16x8 bk0 = *(const bf16x8*)&Kls[cur][row*64 + ((q_     ^ (row & 7)) * 8)];
        const bf16x8 bk1 = *(const bf16x8*)&Kls[cur][row*64 + (((4+q_) ^ (row & 7)) * 8)];
        f32x4 z = {};
        z = mfma16(aq[0], bk0, z);
        s[ni] = mfma16(aq[1], bk1, z);
      }

      // issue next K tile; stays in flight across the counted-vmcnt barrier
      if (kt < qt) STAGE_K(kt + 1, cur ^ 1);

      // --- causal mask: only the diagonal tile ---
      if (kt == qt) {
        const int qrow = w*16 + q_*4;
        #pragma unroll
        for (int ni = 0; ni < 4; ni++) {
          const int kcol = ni*16 + m_;
          #pragma unroll
          for (int r = 0; r < 4; r++)
            if (kcol > qrow + r) s[ni][r] = -1e30f;
        }
      }

      // --- fixed-max exp2 softmax, wave-local P round-trip through LDS ---
      #pragma unroll
      for (int ni = 0; ni < 4; ni++)
        #pragma unroll
        for (int r = 0; r < 4; r++)
          s[ni][r] = exp2f(s[ni][r]);
      #pragma unroll
      for (int r = 0; r < 4; r++)
        lsum[r] += (s[0][r] + s[1][r]) + (s[2][r] + s[3][r]);
      #pragma unroll
      for (int ni = 0; ni < 4; ni++)
        #pragma unroll
        for (int r = 0; r < 4; r++)
          Pls[(w*16 + q_*4 + r) * 76 + ni*16 + m_] = f2bf(s[ni][r]);

      bf16x8 ap[2];
      ap[0] = *(const bf16x8*)&Pls[(w*16 + m_) * 76 + q_*8];
      ap[1] = *(const bf16x8*)&Pls[(w*16 + m_) * 76 + 32 + q_*8];

      // V landed (2 oldest); next-K (2 newest) stays in flight
      if (kt < qt) asm volatile("s_waitcnt vmcnt(2)" ::: "memory");
      else         asm volatile("s_waitcnt vmcnt(0)" ::: "memory");
      __builtin_amdgcn_s_barrier();

      // --- PV from LDS ---
      #pragma unroll
      for (int ni = 0; ni < 4; ni++) {
        const int row = ni*16 + m_;
        const bf16x8 bv0 = *(const bf16x8*)&Vls[row*64 + ((q_     ^ (row & 7)) * 8)];
        const bf16x8 bv1 = *(const bf16x8*)&Vls[row*64 + (((4+q_) ^ (row & 7)) * 8)];
        accO[ni] = mfma16(ap[0], bv0, accO[ni]);
        accO[ni] = mfma16(ap[1], bv1, accO[ni]);
      }

      // next K fully landed + all our LDS reads retired, then handoff barrier
      asm volatile("s_waitcnt vmcnt(0) lgkmcnt(0)" ::: "memory");
      __builtin_amdgcn_s_barrier();
      cur ^= 1;
    }

    // --- epilogue: reduce Sum(p) across the 16 lanes sharing each row, store O/l ---
    #pragma unroll
    for (int r = 0; r < 4; r++) {
      #pragma unroll
      for (int d = 1; d < 16; d <<= 1)
        lsum[r] += __shfl_xor(lsum[r], d, 64);
    }

    const size_t ybase = ((size_t)b * T_ + q0) * C_ + h*64;
    #pragma unroll
    for (int r = 0; r < 4; r++) {
      const int row = w*16 + q_*4 + r;
      const float linv = 1.0f / lsum[r];
      #pragma unroll
      for (int ni = 0; ni < 4; ni++)
        y[ybase + (size_t)row * C_ + ni*16 + m_] = f2bf(accO[ni][r] * linv);
    }
  }
#undef STAGE_K
#undef STAGE_V
}

// ---------------- launch ----------------
extern "C" void kernel_launch(void* const* d_in, const int* in_sizes, int n_in,
                              void* d_out, int out_size, void* d_ws, size_t ws_size,
                              hipStream_t stream) {
  const float* x      = (const float*)d_in[0];
  const float* ln1_g  = (const float*)d_in[1];
  const float* ln1_b  = (const float*)d_in[2];
  const float* w_attn = (const float*)d_in[3];
  const float* b_attn = (const float*)d_in[4];
  const float* w_proj = (const float*)d_in[5];
  const float* b_proj = (const float*)d_in[6];
  const float* ln2_g  = (const float*)d_in[7];
  const float* ln2_b  = (const float*)d_in[8];
  const float* w_fc   = (const float*)d_in[9];
  const float* b_fc   = (const float*)d_in[10];
  const float* w_fc2  = (const float*)d_in[11];
  const float* b_fc2  = (const float*)d_in[12];
  float* out = (float*)d_out;

  char* ws = (char*)d_ws;
  const size_t MB = 1024 * 1024;
  __hip_bfloat16* h      = (__hip_bfloat16*)(ws);                 // 16MB [0,16)
  __hip_bfloat16* qk     = (__hip_bfloat16*)(ws + 16*MB);         // 32MB [16,48)
  __hip_bfloat16* vT     = (__hip_bfloat16*)(ws + 48*MB);         // 16MB [48,64)
  __hip_bfloat16* y      = (__hip_bfloat16*)(ws + 64*MB);         // 16MB [64,80)
  float*          x2     = (float*)        (ws + 80*MB);          // 32MB [80,112)
  __hip_bfloat16* h2     = (__hip_bfloat16*)(ws + 64*MB);         // reuse y slot
  __hip_bfloat16* gbuf   = (__hip_bfloat16*)(ws);                 // 64MB reuse [0,64)
  __hip_bfloat16* wattnT = (__hip_bfloat16*)(ws + 112*MB);        // 6MB
  __hip_bfloat16* wprojT = (__hip_bfloat16*)(ws + 118*MB);        // 2MB
  __hip_bfloat16* wfcT   = (__hip_bfloat16*)(ws + 120*MB);        // 8MB
  __hip_bfloat16* wfc2T  = (__hip_bfloat16*)(ws + 128*MB);        // 8MB

  // weights: [K][N] fp32 -> [N][K] bf16
  transpose_bf16<<<dim3(3*C_/32, C_/32), 256, 0, stream>>>(w_attn, wattnT, C_, 3*C_);
  transpose_bf16<<<dim3(C_/32,  C_/32), 256, 0, stream>>>(w_proj, wprojT, C_, C_);
  transpose_bf16<<<dim3(FF_/32, C_/32), 256, 0, stream>>>(w_fc,   wfcT,   C_, FF_);
  transpose_bf16<<<dim3(C_/32, FF_/32), 256, 0, stream>>>(w_fc2,  wfc2T,  FF_, C_);

  // LN1
  ln_bf16<<<NT_, 256, 0, stream>>>(x, ln1_g, ln1_b, h);
  // QKV: M=8192 N=3072 K=1024, BM=128 -> 64x12 = 768 blocks (3/CU exact)
  gemm256<0,128><<<dim3(768), 512, 0, stream>>>(h, wattnT, b_attn, nullptr, qk, vT, 3*C_, C_);
  // attention (1024 blocks = 64bh x 16 pairs, 4 blocks/CU, LDS-staged K/V)
  flash_attn<<<dim3(1024), 256, 0, stream>>>(qk, vT, y);
  // proj + residual -> x2 (fp32): N=1024, BM=128 -> 64x4 = 256 blocks (1/CU exact)
  gemm256<1,128><<<dim3(256), 512, 0, stream>>>(y, wprojT, b_proj, x, x2, nullptr, C_, C_);
  // LN2
  ln_bf16<<<NT_, 256, 0, stream>>>(x2, ln2_g, ln2_b, h2);
  // FC + gelu: N=4096, BM=256 -> 32x16 = 512 blocks (2/CU exact)
  gemm256<2,256><<<dim3(512), 512, 0, stream>>>(h2, wfcT, b_fc, nullptr, gbuf, nullptr, FF_, C_);
  // FC2 + residual -> out (fp32): N=1024 K=4096, BM=128 -> 256 blocks
  gemm256<3,128><<<dim3(256), 512, 0, stream>>>(gbuf, wfc2T, b_fc2, x2, out, nullptr, C_, FF_);
}